// Round 5
// baseline (887.881 us; speedup 1.0000x reference)
//
#include <hip/hip_runtime.h>
#include <cstdint>

typedef float  f32x4  __attribute__((ext_vector_type(4)));
typedef __bf16 bf16x8 __attribute__((ext_vector_type(8)));
typedef int    i32x4  __attribute__((ext_vector_type(4)));
typedef unsigned short u16;
typedef u16 u16x4 __attribute__((ext_vector_type(4)));

#define TT 512

// ---------- helpers ----------
__device__ __forceinline__ u16 f2bf(float f) {
  unsigned u = __builtin_bit_cast(unsigned, f);
  unsigned r = u + 0x7fffu + ((u >> 16) & 1u);   // RNE
  return (u16)(r >> 16);
}
__device__ __forceinline__ float bflo(unsigned d) { return __builtin_bit_cast(float, d << 16); }
__device__ __forceinline__ float bfhi(unsigned d) { return __builtin_bit_cast(float, d & 0xffff0000u); }
__device__ __forceinline__ float rcpf(float x) { return __builtin_amdgcn_rcpf(x); }
__device__ __forceinline__ float fsig(float x) { return rcpf(1.f + __expf(-x)); }
__device__ __forceinline__ float ftanh(float x) { return 1.f - 2.f * rcpf(1.f + __expf(2.f * x)); }
__device__ __forceinline__ void gload_lds16(const u16* g, u16* l) {
  __builtin_amdgcn_global_load_lds((const __attribute__((address_space(1))) void*)(g),
                                   (__attribute__((address_space(3))) void*)(l), 16, 0, 0);
}

// ---------- prep: x (N,T,D) fp32 -> xb (T,N,D) bf16, 4 elems/thread ----------
__global__ __launch_bounds__(256) void prep_x(const float* __restrict__ x, u16* __restrict__ xb) {
  long o = ((long)blockIdx.x * 256 + threadIdx.x) * 4;   // 33,554,432 total elems
  int d = (int)(o & 255);
  int n = (int)((o >> 8) & 255);
  int t = (int)(o >> 16);
  const float4 v = *(const float4*)(x + ((long)n << 17) + ((long)t << 8) + d);
  u16x4 p;
  p[0] = f2bf(v.x); p[1] = f2bf(v.y); p[2] = f2bf(v.z); p[3] = f2bf(v.w);
  *(u16x4*)(xb + o) = p;
}

// ---------- prep: Wx -> bf16 transposed; Wh -> i8 per-col quant; bias sum ----------
__global__ __launch_bounds__(256) void prep_w(
    const float* __restrict__ wii, const float* __restrict__ whi,
    const float* __restrict__ wif, const float* __restrict__ whf,
    const float* __restrict__ wig, const float* __restrict__ whg,
    const float* __restrict__ wio, const float* __restrict__ who,
    const float* __restrict__ bii, const float* __restrict__ bhi,
    const float* __restrict__ bif, const float* __restrict__ bhf,
    const float* __restrict__ big_, const float* __restrict__ bhg,
    const float* __restrict__ bio, const float* __restrict__ bho,
    u16* __restrict__ Wxb, signed char* __restrict__ Whq,
    float* __restrict__ wscale, float* __restrict__ bsum) {
  __shared__ float red[256];
  int b = blockIdx.x;
  int tid = threadIdx.x;
  if (b < 1024) {                 // Wxb_t[col][d] = w_x{G}[d][h], col = G*256+h
    const float* wx[4] = {wii, wif, wig, wio};
    int G = b >> 8, h = b & 255;
    Wxb[b * 256 + tid] = f2bf(wx[G][tid * 256 + h]);
  } else if (b < 2048) {          // Whq[col][u] = quant(w_h{G}[u][h]), per-col scale
    const float* wh[4] = {whi, whf, whg, who};
    int cidx = b - 1024;
    int G = cidx >> 8, h = cidx & 255;
    float w = wh[G][tid * 256 + h];
    red[tid] = fabsf(w);
    __syncthreads();
    for (int s = 128; s > 0; s >>= 1) {
      if (tid < s) red[tid] = fmaxf(red[tid], red[tid + s]);
      __syncthreads();
    }
    float mx = red[0];
    float scale = (mx > 0.f) ? mx * (1.f / 127.f) : 1.f;
    float qf = rintf(w / scale);
    qf = fminf(127.f, fmaxf(-127.f, qf));
    Whq[cidx * 256 + tid] = (signed char)(int)qf;
    if (tid == 0) wscale[cidx] = scale * (1.f / 127.f);   // combined w-scale * h-scale
  } else {
    const float* bx[4] = {bii, bif, big_, bio};
    const float* bh[4] = {bhi, bhf, bhg, bho};
    for (int G = 0; G < 4; ++G) bsum[G * 256 + tid] = bx[G][tid] + bh[G][tid];
  }
}

// ---------- fused: 128 producer wgs (xW GEMM, t-ordered) + 128 rec wgs ----------
// Cooperative grid 256 x 512, 1 block/CU. bid&7 = XCD slot.
// Producer (j>=16): column n8 = xcd (B tile L2-local), t = (j-16) + 16*it.
//   Tile M=256 x N=128 x K=256, bf16 MFMA, epilogue packs to MFMA-C layout,
//   then __syncthreads + agent-release fence + flag[t*8+n8]=1.
// Rec (j<16): round-4 structure (Wh i8 in AGPRs, 1 cell/lane, raw lgkm-only
//   barrier). xW loads are AGENT-scope (L2-bypass) so no acquire fences;
//   per-wave watermark Wv advances in chunks of 8 t's via one relaxed agent
//   flag-load per step, evaluated one step later (off critical path).
__global__ __launch_bounds__(512, 2) void lstm_fused(
    const u16* __restrict__ xb, const u16* __restrict__ Wxb,
    const float* __restrict__ bsum,
    const signed char* __restrict__ Whq, const float* __restrict__ wscale,
    u16* __restrict__ xWp, unsigned* __restrict__ flags,
    float* __restrict__ out) {
  __shared__ __align__(16) char smem[24576];
  int bid = blockIdx.x;
  int xcd = bid & 7;
  int j = bid >> 3;              // 0..31
  int tid = threadIdx.x;
  int l = tid & 63;

  if (j >= 16) {
    // ================= producer =================
    int toff = j - 16;           // 0..15: handles t = toff + 16*it
    int n8 = xcd;                // 128-col block
    u16* As = (u16*)smem;        // 256 x 32 bf16 (16 KB)
    u16* Bs = (u16*)(smem + 16384);   // 128 x 32 bf16 (8 KB)
    const u16* Bb = Wxb + (size_t)n8 * 32768;
    int row = tid >> 2, ch = tid & 3;
    int w = tid >> 6, wm = w >> 1, wn = w & 1;
    for (int it = 0; it < 32; ++it) {
      int t = toff + (it << 4);
      const u16* Ab = xb + (size_t)t * 65536;
      f32x4 acc[4][4];
#pragma unroll
      for (int i = 0; i < 4; ++i)
#pragma unroll
        for (int jj = 0; jj < 4; ++jj) acc[i][jj] = (f32x4){0.f, 0.f, 0.f, 0.f};
      for (int ko = 0; ko < 8; ++ko) {
        __syncthreads();
        gload_lds16(Ab + (size_t)row * 256 + ko * 32 + ch * 8, As + tid * 8);
        gload_lds16(Ab + (size_t)(row + 128) * 256 + ko * 32 + ch * 8, As + 4096 + tid * 8);
        gload_lds16(Bb + (size_t)row * 256 + ko * 32 + ch * 8, Bs + tid * 8);
        __syncthreads();
        bf16x8 bfr[4];
#pragma unroll
        for (int nt = 0; nt < 4; ++nt)
          bfr[nt] = *reinterpret_cast<const bf16x8*>(Bs + (wn * 64 + nt * 16 + (l & 15)) * 32 + (l >> 4) * 8);
#pragma unroll
        for (int mt = 0; mt < 4; ++mt) {
          bf16x8 af = *reinterpret_cast<const bf16x8*>(As + (wm * 64 + mt * 16 + (l & 15)) * 32 + (l >> 4) * 8);
#pragma unroll
          for (int nt = 0; nt < 4; ++nt)
            acc[mt][nt] = __builtin_amdgcn_mfma_f32_16x16x32_bf16(af, bfr[nt], acc[mt][nt], 0, 0, 0);
        }
      }
#pragma unroll
      for (int mt = 0; mt < 4; ++mt) {
        int tm = t * 16 + wm * 4 + mt;
#pragma unroll
        for (int nt = 0; nt < 4; ++nt) {
          int tn = n8 * 8 + wn * 4 + nt;
          float bv = bsum[tn * 16 + (l & 15)];
          u16x4 pk;
#pragma unroll
          for (int r = 0; r < 4; ++r) pk[r] = f2bf(acc[mt][nt][r] + bv);
          *reinterpret_cast<u16x4*>(xWp + ((size_t)(tm * 64 + tn) * 256 + l * 4)) = pk;
        }
      }
      __syncthreads();   // all waves' stores drained (vmcnt 0) before flag
      if (tid == 0) {
        __builtin_amdgcn_fence(__ATOMIC_RELEASE, "agent");   // L2 writeback
        __hip_atomic_store(flags + t * 8 + n8, 1u, __ATOMIC_RELAXED, __HIP_MEMORY_SCOPE_AGENT);
      }
    }
    return;
  }

  // ================= rec =================
  signed char* hb0 = (signed char*)smem;          // 2 x 576 B
  signed char* hb1 = (signed char*)smem + 576;
  int q8 = j & 7, tsel = j >> 3;
  int G = xcd * 2 + tsel;        // 16-row tile id; 8 co-XCD sharers
  int wid = tid >> 6;
  int c = l & 15, q = (l >> 4) & 3;
  int tt = q >> 1, rsel = q & 1;

  for (int i = tid; i < 288; i += 512) ((int*)smem)[i] = 0;

  // Wh i8 fragments: [gate][tt-tile][kstep] -> forced into AGPRs by asm "a" use
  i32x4 bw[4][2][4];
#pragma unroll
  for (int g = 0; g < 4; ++g)
#pragma unroll
    for (int ttl = 0; ttl < 2; ++ttl) {
      int col = g * 256 + wid * 32 + ttl * 16 + c;
#pragma unroll
      for (int ks = 0; ks < 4; ++ks)
        bw[g][ttl][ks] = *reinterpret_cast<const i32x4*>(Whq + (size_t)col * 256 + ks * 64 + q * 16);
    }
  float sc8[4];
#pragma unroll
  for (int g = 0; g < 4; ++g) sc8[g] = wscale[g * 256 + wid * 32 + tt * 16 + c];

  const char* xbase = (const char*)xWp + (size_t)G * 32768;
  int xoff[4];
#pragma unroll
  for (int g = 0; g < 4; ++g) {
    int tn = g * 16 + wid * 2 + tt;
    xoff[g] = tn * 512 + (((q8 >> 1) * 16 + c) * 8) + (q8 & 1) * 4;
  }

  // watermark spin-up: need t=0 and t=1 ready before first loads
  int Wv = -1;
  unsigned pv = 0;
  {
    int guard = 0;
    while (Wv < 1 && ++guard < 50000000) {
      int td = Wv + 1 + (l >> 3);
      int tdc = td <= 511 ? td : 511;
      unsigned v = __hip_atomic_load(flags + tdc * 8 + (l & 7),
                                     __ATOMIC_RELAXED, __HIP_MEMORY_SCOPE_AGENT);
      if (td > 511) v = 1u;
      if (__all((int)(v == 1u))) { Wv += 8; if (Wv > 511) Wv = 511; }
    }
  }
  unsigned xw0[4], xw1[4];
#pragma unroll
  for (int g = 0; g < 4; ++g)
    xw0[g] = __hip_atomic_load((const unsigned*)(xbase + xoff[g]),
                               __ATOMIC_RELAXED, __HIP_MEMORY_SCOPE_AGENT);
  xbase += 524288;   // -> t=1

  i32x4 zacc = (i32x4){0, 0, 0, 0};
  float cs = 0.f, hh = 0.f;
  __syncthreads();

#define STEP(CUR, XW_CUR, XW_NXT, TCUR)                                         \
  {                                                                             \
    if (Wv < 511) {   /* opportunistic advance; pv issued last step */          \
      if (__all((int)(pv == 1u))) { Wv += 8; if (Wv > 511) Wv = 511; }          \
      if (Wv < 511) {                                                           \
        int td = Wv + 1 + (l >> 3);                                             \
        int tdc = td <= 511 ? td : 511;                                         \
        unsigned v = __hip_atomic_load(flags + tdc * 8 + (l & 7),               \
                        __ATOMIC_RELAXED, __HIP_MEMORY_SCOPE_AGENT);            \
        pv = (td > 511) ? 1u : v;                                               \
      }                                                                         \
    }                                                                           \
    if (Wv < (TCUR) + 1 && Wv < 511) {   /* blocking fallback (rare) */         \
      int guard = 0;                                                            \
      do {                                                                      \
        int td = Wv + 1 + (l >> 3);                                             \
        int tdc = td <= 511 ? td : 511;                                         \
        unsigned v = __hip_atomic_load(flags + tdc * 8 + (l & 7),               \
                        __ATOMIC_RELAXED, __HIP_MEMORY_SCOPE_AGENT);            \
        if (td > 511) v = 1u;                                                   \
        if (__all((int)(v == 1u))) { Wv += 8; if (Wv > 511) Wv = 511; }         \
      } while (Wv < (TCUR) + 1 && Wv < 511 && ++guard < 20000000);              \
      pv = 0u;                                                                  \
    }                                                                           \
    _Pragma("unroll")                                                           \
    for (int g = 0; g < 4; ++g)                                                 \
      XW_NXT[g] = __hip_atomic_load((const unsigned*)(xbase + xoff[g]),         \
                      __ATOMIC_RELAXED, __HIP_MEMORY_SCOPE_AGENT);              \
    const signed char* hr = (CUR) ? hb0 : hb1;                                  \
    i32x4 acc[4][2];                                                            \
    {                                                                           \
      i32x4 a0 = *(const i32x4*)(hr + (c & 1) * 288 + q * 16);                  \
      _Pragma("unroll")                                                         \
      for (int g = 0; g < 4; ++g) {                                             \
        __asm__("v_mfma_i32_16x16x64_i8 %0, %1, %2, %3"                         \
                : "=&v"(acc[g][0]) : "v"(a0), "a"(bw[g][0][0]), "v"(zacc));     \
        __asm__("v_mfma_i32_16x16x64_i8 %0, %1, %2, %3"                         \
                : "=&v"(acc[g][1]) : "v"(a0), "a"(bw[g][1][0]), "v"(zacc));     \
      }                                                                         \
    }                                                                           \
    _Pragma("unroll")                                                           \
    for (int ks = 1; ks < 4; ++ks) {                                            \
      i32x4 a = *(const i32x4*)(hr + (c & 1) * 288 + ks * 64 + q * 16);         \
      _Pragma("unroll")                                                         \
      for (int g = 0; g < 4; ++g) {                                             \
        __asm__("v_mfma_i32_16x16x64_i8 %0, %1, %2, %0"                         \
                : "+v"(acc[g][0]) : "v"(a), "a"(bw[g][0][ks]));                 \
        __asm__("v_mfma_i32_16x16x64_i8 %0, %1, %2, %0"                         \
                : "+v"(acc[g][1]) : "v"(a), "a"(bw[g][1][ks]));                 \
      }                                                                         \
    }                                                                           \
    __asm__ volatile("s_nop 7\n\ts_nop 7\n\ts_nop 7");  /* MFMA->VALU hazard */ \
    float a4[4];                                                                \
    _Pragma("unroll")                                                           \
    for (int g = 0; g < 4; ++g) {                                               \
      int e = tt ? (rsel ? acc[g][1][1] : acc[g][1][0])                         \
                 : (rsel ? acc[g][0][1] : acc[g][0][0]);                        \
      unsigned d = XW_CUR[g];                                                   \
      float xv = rsel ? bfhi(d) : bflo(d);                                      \
      a4[g] = (float)e * sc8[g] + xv;                                           \
    }                                                                           \
    float gi = fsig(a4[0]);                                                     \
    float gf = fsig(a4[1]);                                                     \
    float gg = ftanh(a4[2]);                                                    \
    float go = fsig(a4[3]);                                                     \
    cs = gf * cs + gi * gg;                                                     \
    hh = go * ftanh(cs);                                                        \
    int hq = (int)rintf(hh * 127.f);                                            \
    ((CUR) ? hb1 : hb0)[rsel * 288 + wid * 32 + tt * 16 + c] = (signed char)hq; \
    xbase += 524288;                                                            \
    __builtin_amdgcn_s_waitcnt(0xC07F);  /* lgkmcnt(0) only, vmcnt in flight */ \
    __builtin_amdgcn_s_barrier();                                               \
  }

  for (int t = 0; t < TT; t += 2) {
    STEP(0, xw0, xw1, t)
    STEP(1, xw1, xw0, t + 1)
  }
#undef STEP

  {
    int n = G * 16 + q8 * 2 + rsel;
    int hu = wid * 32 + tt * 16 + c;
    out[(size_t)n * 256 + hu] = hh;
    out[65536 + (size_t)n * 256 + hu] = cs;
  }
}

// ---------- launch ----------
extern "C" void kernel_launch(void* const* d_in, const int* in_sizes, int n_in,
                              void* d_out, int out_size, void* d_ws, size_t ws_size,
                              hipStream_t stream) {
  const float* x   = (const float*)d_in[0];
  const float* wii = (const float*)d_in[1];
  const float* whi = (const float*)d_in[2];
  const float* wif = (const float*)d_in[3];
  const float* whf = (const float*)d_in[4];
  const float* wig = (const float*)d_in[5];
  const float* whg = (const float*)d_in[6];
  const float* wio = (const float*)d_in[7];
  const float* who = (const float*)d_in[8];
  const float* bii = (const float*)d_in[9];
  const float* bhi = (const float*)d_in[10];
  const float* bif = (const float*)d_in[11];
  const float* bhf = (const float*)d_in[12];
  const float* big_ = (const float*)d_in[13];
  const float* bhg = (const float*)d_in[14];
  const float* bio = (const float*)d_in[15];
  const float* bho = (const float*)d_in[16];

  char* ws = (char*)d_ws;
  u16*   xb     = (u16*)(ws);                         // 67,108,864 B
  u16*   Wxb    = (u16*)(ws + 67108864);              //    524,288 B
  signed char* Whq = (signed char*)(ws + 67633152);   //    262,144 B
  float* wscale = (float*)(ws + 67895296);            //      4,096 B
  float* bsum   = (float*)(ws + 67899392);            //      4,096 B
  unsigned* flags = (unsigned*)(ws + 67903488);       //     16,384 B
  u16*   xWp    = (u16*)(ws + 67919872);              // 268,435,456 B + 576 KB pad
  float* out = (float*)d_out;

  hipMemsetAsync(flags, 0, 16384, stream);
  prep_x<<<32768, 256, 0, stream>>>(x, xb);
  prep_w<<<2049, 256, 0, stream>>>(wii, whi, wif, whf, wig, whg, wio, who,
                                   bii, bhi, bif, bhf, big_, bhg, bio, bho,
                                   Wxb, Whq, wscale, bsum);

  void* args[8];
  const u16* xbA = xb; const u16* WxbA = Wxb; const float* bsumA = bsum;
  const signed char* WhqA = Whq; const float* wscaleA = wscale;
  u16* xWpA = xWp; unsigned* flagsA = flags; float* outA = (float*)d_out;
  args[0] = (void*)&xbA;
  args[1] = (void*)&WxbA;
  args[2] = (void*)&bsumA;
  args[3] = (void*)&WhqA;
  args[4] = (void*)&wscaleA;
  args[5] = (void*)&xWpA;
  args[6] = (void*)&flagsA;
  args[7] = (void*)&outA;
  hipLaunchCooperativeKernel((const void*)lstm_fused, dim3(256), dim3(512), args, 0, stream);
}

// Round 6
// 794.230 us; speedup vs baseline: 1.1179x; 1.1179x over previous
//
#include <hip/hip_runtime.h>
#include <cstdint>

typedef float  f32x4  __attribute__((ext_vector_type(4)));
typedef __bf16 bf16x8 __attribute__((ext_vector_type(8)));
typedef int    i32x4  __attribute__((ext_vector_type(4)));
typedef unsigned short u16;
typedef u16 u16x4 __attribute__((ext_vector_type(4)));

#define TT 512

// ---------- helpers ----------
__device__ __forceinline__ u16 f2bf(float f) {
  unsigned u = __builtin_bit_cast(unsigned, f);
  unsigned r = u + 0x7fffu + ((u >> 16) & 1u);   // RNE
  return (u16)(r >> 16);
}
__device__ __forceinline__ float bflo(unsigned d) { return __builtin_bit_cast(float, d << 16); }
__device__ __forceinline__ float bfhi(unsigned d) { return __builtin_bit_cast(float, d & 0xffff0000u); }
__device__ __forceinline__ float rcpf(float x) { return __builtin_amdgcn_rcpf(x); }
__device__ __forceinline__ float fsig(float x) { return rcpf(1.f + __expf(-x)); }
__device__ __forceinline__ float ftanh(float x) { return 1.f - 2.f * rcpf(1.f + __expf(2.f * x)); }
__device__ __forceinline__ void gload_lds16(const u16* g, u16* l) {
  __builtin_amdgcn_global_load_lds((const __attribute__((address_space(1))) void*)(g),
                                   (__attribute__((address_space(3))) void*)(l), 16, 0, 0);
}

// ---------- fused prep: x->bf16 transpose + weight quant/transpose + bias ----------
// blocks 0..32767: x (N,T,D) fp32 -> xb (T,N,D) bf16, 4 elems/thread
// blocks 32768..34816: Wx -> bf16 transposed; Wh -> i8 per-col quant; bias sum
__global__ __launch_bounds__(256) void prep_all(
    const float* __restrict__ x, u16* __restrict__ xb,
    const float* __restrict__ wii, const float* __restrict__ whi,
    const float* __restrict__ wif, const float* __restrict__ whf,
    const float* __restrict__ wig, const float* __restrict__ whg,
    const float* __restrict__ wio, const float* __restrict__ who,
    const float* __restrict__ bii, const float* __restrict__ bhi,
    const float* __restrict__ bif, const float* __restrict__ bhf,
    const float* __restrict__ big_, const float* __restrict__ bhg,
    const float* __restrict__ bio, const float* __restrict__ bho,
    u16* __restrict__ Wxb, signed char* __restrict__ Whq,
    float* __restrict__ wscale, float* __restrict__ bsum) {
  __shared__ float red[256];
  int bid = blockIdx.x;
  int tid = threadIdx.x;
  if (bid < 32768) {
    long o = ((long)bid * 256 + tid) * 4;   // 33,554,432 total elems
    int d = (int)(o & 255);
    int n = (int)((o >> 8) & 255);
    int t = (int)(o >> 16);
    const float4 v = *(const float4*)(x + ((long)n << 17) + ((long)t << 8) + d);
    u16x4 p;
    p[0] = f2bf(v.x); p[1] = f2bf(v.y); p[2] = f2bf(v.z); p[3] = f2bf(v.w);
    *(u16x4*)(xb + o) = p;
    return;
  }
  int b = bid - 32768;
  if (b < 1024) {                 // Wxb_t[col][d] = w_x{G}[d][h], col = G*256+h
    const float* wx[4] = {wii, wif, wig, wio};
    int G = b >> 8, h = b & 255;
    Wxb[b * 256 + tid] = f2bf(wx[G][tid * 256 + h]);
  } else if (b < 2048) {          // Whq[col][u] = quant(w_h{G}[u][h]), per-col scale
    const float* wh[4] = {whi, whf, whg, who};
    int cidx = b - 1024;
    int G = cidx >> 8, h = cidx & 255;
    float w = wh[G][tid * 256 + h];
    red[tid] = fabsf(w);
    __syncthreads();
    for (int s = 128; s > 0; s >>= 1) {
      if (tid < s) red[tid] = fmaxf(red[tid], red[tid + s]);
      __syncthreads();
    }
    float mx = red[0];
    float scale = (mx > 0.f) ? mx * (1.f / 127.f) : 1.f;
    float qf = rintf(w / scale);
    qf = fminf(127.f, fmaxf(-127.f, qf));
    Whq[cidx * 256 + tid] = (signed char)(int)qf;
    if (tid == 0) wscale[cidx] = scale * (1.f / 127.f);   // combined w-scale * h-scale
  } else {
    const float* bx[4] = {bii, bif, big_, bio};
    const float* bh[4] = {bhi, bhf, bhg, bho};
    for (int G = 0; G < 4; ++G) bsum[G * 256 + tid] = bx[G][tid] + bh[G][tid];
  }
}

// ---------- phase 1: xWp = pack(xb @ Wx + b), 128x128 tile ----------
// __launch_bounds__(256,4): cap VGPR<=128 -> 4 blocks/CU co-resident -> 4
// independent k-loop streams/CU hide the global_load_lds latency by TLP
// (K=256 means only 8 k-iters/block; single-stream is latency-bound).
// Output tile-packed (MFMA C layout): xWp[(tm*64+tn)*256 + l*4 + r],
// lane l = q*16+c -> rows q*4+r, col c of tile (tm,tn).
__global__ __launch_bounds__(256, 4) void gemm_xw(const u16* __restrict__ A, const u16* __restrict__ Bt,
                                                  const float* __restrict__ bias, u16* __restrict__ xWp) {
  __shared__ u16 As[128 * 32];
  __shared__ u16 Bs[128 * 32];
  int bid = blockIdx.x;
  int bm = bid & 1023, bn = bid >> 10;
  int tid = threadIdx.x;
  int l = tid & 63, w = tid >> 6;
  int wm = w >> 1, wn = w & 1;
  f32x4 acc[4][4];
#pragma unroll
  for (int i = 0; i < 4; ++i)
#pragma unroll
    for (int j = 0; j < 4; ++j) acc[i][j] = (f32x4){0.f, 0.f, 0.f, 0.f};

  const u16* Ab = A + (size_t)bm * 128 * 256;
  const u16* Bb = Bt + (size_t)bn * 128 * 256;
  int row = tid >> 2;
  int ch = tid & 3;
  for (int ko = 0; ko < 8; ++ko) {
    __syncthreads();
    gload_lds16(Ab + (size_t)row * 256 + ko * 32 + ch * 8, As + tid * 8);
    gload_lds16(Ab + (size_t)(row + 64) * 256 + ko * 32 + ch * 8, As + 2048 + tid * 8);
    gload_lds16(Bb + (size_t)row * 256 + ko * 32 + ch * 8, Bs + tid * 8);
    gload_lds16(Bb + (size_t)(row + 64) * 256 + ko * 32 + ch * 8, Bs + 2048 + tid * 8);
    __syncthreads();
    bf16x8 af[4], bfr[4];
#pragma unroll
    for (int mt = 0; mt < 4; ++mt)
      af[mt] = *reinterpret_cast<const bf16x8*>(As + (wm * 64 + mt * 16 + (l & 15)) * 32 + (l >> 4) * 8);
#pragma unroll
    for (int nt = 0; nt < 4; ++nt)
      bfr[nt] = *reinterpret_cast<const bf16x8*>(Bs + (wn * 64 + nt * 16 + (l & 15)) * 32 + (l >> 4) * 8);
#pragma unroll
    for (int mt = 0; mt < 4; ++mt)
#pragma unroll
      for (int nt = 0; nt < 4; ++nt)
        acc[mt][nt] = __builtin_amdgcn_mfma_f32_16x16x32_bf16(af[mt], bfr[nt], acc[mt][nt], 0, 0, 0);
  }
#pragma unroll
  for (int mt = 0; mt < 4; ++mt) {
    int tm = bm * 8 + wm * 4 + mt;
#pragma unroll
    for (int nt = 0; nt < 4; ++nt) {
      int tn = bn * 8 + wn * 4 + nt;
      float bv = bias[tn * 16 + (l & 15)];
      u16x4 pk;
#pragma unroll
      for (int r = 0; r < 4; ++r) pk[r] = f2bf(acc[mt][nt][r] + bv);
      *reinterpret_cast<u16x4*>(xWp + ((size_t)(tm * 64 + tn) * 256 + l * 4)) = pk;
    }
  }
}

// ---------- phase 2: recurrence, CU-local, AGPR-pinned weights (round-4, frozen) ----------
// 128 wgs x 512 threads. wg owns 2 batch rows (A rows replicated x8).
// Wave wid owns hidden units wid*32..+31, all 4 gates: Wh i8 slice pinned in
// 128 AGPRs per lane via inline-asm MFMA "a" constraints (no spill possible).
// 1 LSTM cell per lane -> 5 exp + 5 rcp per lane per step.
// Step body macro-expanded with compile-time CUR: no dynamic register-array
// indexing anywhere (anti-scratch). One lgkm-only raw barrier per step.
__global__ __launch_bounds__(512, 2) void lstm_rec(const signed char* __restrict__ Whq,
                                                   const float* __restrict__ wscale,
                                                   const u16* __restrict__ xWp,
                                                   float* __restrict__ out) {
  __shared__ __align__(16) signed char hb[2][576];   // 2 x (2 rows x 288B)
  int p = blockIdx.x;            // 0..127
  int xcd = p & 7, q8 = (p >> 3) & 7, tsel = p >> 6;
  int G = xcd * 2 + tsel;        // 16-row tile id; 8 co-XCD sharers
  int tid = threadIdx.x;
  int wid = tid >> 6, l = tid & 63;
  int c = l & 15, q = (l >> 4) & 3;
  int tt = q >> 1, rsel = q & 1;

  for (int i = tid; i < 288; i += 512) ((int*)hb)[i] = 0;

  // Wh i8 fragments: [gate][tt-tile][kstep] -> forced into AGPRs by asm "a" use
  i32x4 bw[4][2][4];
#pragma unroll
  for (int g = 0; g < 4; ++g)
#pragma unroll
    for (int ttl = 0; ttl < 2; ++ttl) {
      int col = g * 256 + wid * 32 + ttl * 16 + c;
#pragma unroll
      for (int ks = 0; ks < 4; ++ks)
        bw[g][ttl][ks] = *reinterpret_cast<const i32x4*>(Whq + (size_t)col * 256 + ks * 64 + q * 16);
    }
  float sc8[4];
#pragma unroll
  for (int g = 0; g < 4; ++g) sc8[g] = wscale[g * 256 + wid * 32 + tt * 16 + c];

  // xW: tile tm = t*16 + G; this wg's rows are regs {2*(q8&1), +1} of quad q8>>1
  const char* xbase = (const char*)xWp + (size_t)G * 32768;
  int xoff[4];
#pragma unroll
  for (int g = 0; g < 4; ++g) {
    int tn = g * 16 + wid * 2 + tt;
    xoff[g] = tn * 512 + (((q8 >> 1) * 16 + c) * 8) + (q8 & 1) * 4;
  }
  unsigned xw0[4], xw1[4];
#pragma unroll
  for (int g = 0; g < 4; ++g) xw0[g] = *(const unsigned*)(xbase + xoff[g]);   // t=0
  xbase += 524288;   // -> t=1

  i32x4 zacc = (i32x4){0, 0, 0, 0};
  float cs = 0.f, hh = 0.f;
  __syncthreads();

#define STEP(CUR, XW_CUR, XW_NXT)                                               \
  {                                                                             \
    _Pragma("unroll")                                                           \
    for (int g = 0; g < 4; ++g) XW_NXT[g] = *(const unsigned*)(xbase + xoff[g]);\
    const signed char* hr = hb[CUR ^ 1];                                        \
    i32x4 acc[4][2];                                                            \
    {                                                                           \
      i32x4 a0 = *(const i32x4*)(hr + (c & 1) * 288 + q * 16);                  \
      _Pragma("unroll")                                                         \
      for (int g = 0; g < 4; ++g) {                                             \
        __asm__("v_mfma_i32_16x16x64_i8 %0, %1, %2, %3"                         \
                : "=&v"(acc[g][0]) : "v"(a0), "a"(bw[g][0][0]), "v"(zacc));     \
        __asm__("v_mfma_i32_16x16x64_i8 %0, %1, %2, %3"                         \
                : "=&v"(acc[g][1]) : "v"(a0), "a"(bw[g][1][0]), "v"(zacc));     \
      }                                                                         \
    }                                                                           \
    _Pragma("unroll")                                                           \
    for (int ks = 1; ks < 4; ++ks) {                                            \
      i32x4 a = *(const i32x4*)(hr + (c & 1) * 288 + ks * 64 + q * 16);         \
      _Pragma("unroll")                                                         \
      for (int g = 0; g < 4; ++g) {                                             \
        __asm__("v_mfma_i32_16x16x64_i8 %0, %1, %2, %0"                         \
                : "+v"(acc[g][0]) : "v"(a), "a"(bw[g][0][ks]));                 \
        __asm__("v_mfma_i32_16x16x64_i8 %0, %1, %2, %0"                         \
                : "+v"(acc[g][1]) : "v"(a), "a"(bw[g][1][ks]));                 \
      }                                                                         \
    }                                                                           \
    __asm__ volatile("s_nop 7\n\ts_nop 7\n\ts_nop 7");  /* MFMA->VALU hazard */ \
    float a4[4];                                                                \
    _Pragma("unroll")                                                           \
    for (int g = 0; g < 4; ++g) {                                               \
      int e = tt ? (rsel ? acc[g][1][1] : acc[g][1][0])                         \
                 : (rsel ? acc[g][0][1] : acc[g][0][0]);                        \
      unsigned d = XW_CUR[g];                                                   \
      float xv = rsel ? bfhi(d) : bflo(d);                                      \
      a4[g] = (float)e * sc8[g] + xv;                                           \
    }                                                                           \
    float gi = fsig(a4[0]);                                                     \
    float gf = fsig(a4[1]);                                                     \
    float gg = ftanh(a4[2]);                                                    \
    float go = fsig(a4[3]);                                                     \
    cs = gf * cs + gi * gg;                                                     \
    hh = go * ftanh(cs);                                                        \
    int hq = (int)rintf(hh * 127.f);                                            \
    hb[CUR][rsel * 288 + wid * 32 + tt * 16 + c] = (signed char)hq;             \
    xbase += 524288;                                                            \
    __builtin_amdgcn_s_waitcnt(0xC07F);  /* lgkmcnt(0) only, vmcnt in flight */ \
    __builtin_amdgcn_s_barrier();                                               \
  }

  for (int t = 0; t < TT; t += 2) {
    STEP(0, xw0, xw1)
    STEP(1, xw1, xw0)
  }
#undef STEP

  {
    int n = G * 16 + q8 * 2 + rsel;
    int hu = wid * 32 + tt * 16 + c;
    out[(size_t)n * 256 + hu] = hh;
    out[65536 + (size_t)n * 256 + hu] = cs;
  }
}

// ---------- launch ----------
extern "C" void kernel_launch(void* const* d_in, const int* in_sizes, int n_in,
                              void* d_out, int out_size, void* d_ws, size_t ws_size,
                              hipStream_t stream) {
  const float* x   = (const float*)d_in[0];
  const float* wii = (const float*)d_in[1];
  const float* whi = (const float*)d_in[2];
  const float* wif = (const float*)d_in[3];
  const float* whf = (const float*)d_in[4];
  const float* wig = (const float*)d_in[5];
  const float* whg = (const float*)d_in[6];
  const float* wio = (const float*)d_in[7];
  const float* who = (const float*)d_in[8];
  const float* bii = (const float*)d_in[9];
  const float* bhi = (const float*)d_in[10];
  const float* bif = (const float*)d_in[11];
  const float* bhf = (const float*)d_in[12];
  const float* big_ = (const float*)d_in[13];
  const float* bhg = (const float*)d_in[14];
  const float* bio = (const float*)d_in[15];
  const float* bho = (const float*)d_in[16];

  char* ws = (char*)d_ws;
  u16*   xb     = (u16*)(ws);                         // 67,108,864 B
  u16*   Wxb    = (u16*)(ws + 67108864);              //    524,288 B
  signed char* Whq = (signed char*)(ws + 67633152);   //    262,144 B
  float* wscale = (float*)(ws + 67895296);            //      4,096 B
  float* bsum   = (float*)(ws + 67899392);            //      4,096 B
  u16*   xWp    = (u16*)(ws + 67903488);              // 268,435,456 B + 576 KB prefetch pad
  float* out = (float*)d_out;

  prep_all<<<34817, 256, 0, stream>>>(x, xb,
                                      wii, whi, wif, whf, wig, whg, wio, who,
                                      bii, bhi, bif, bhf, big_, bhg, bio, bho,
                                      Wxb, Whq, wscale, bsum);
  gemm_xw<<<8192, 256, 0, stream>>>(xb, Wxb, bsum, xWp);
  lstm_rec<<<128, 512, 0, stream>>>(Whq, wscale, xWp, out);
}